// Round 10
// baseline (1053.894 us; speedup 1.0000x reference)
//
#include <hip/hip_runtime.h>
#include <stdint.h>

#define N_NODES 4096
#define NGRAPH 8
#define NPTS 512
#define KNN 64
#define EPSN 1e-5f

typedef _Float16 f16x8 __attribute__((ext_vector_type(8)));
typedef float f32x4 __attribute__((ext_vector_type(4)));

__device__ __forceinline__ unsigned short f2h(float f) {
    _Float16 h = (_Float16)f;   // RNE, v_cvt_f16_f32
    union { _Float16 h; unsigned short u; } cv; cv.h = h;
    return cv.u;
}

// ---------------- kNN: one block per dst point, bitonic sort of 512 (d2,idx) keys ----------------
__global__ __launch_bounds__(512) void knn_kernel(const float* __restrict__ pos, int* __restrict__ knn_out) {
#pragma clang fp contract(off)
    __shared__ float px[NPTS], py[NPTS], pz[NPTS];
    __shared__ unsigned long long keys[NPTS];
    int b = blockIdx.x >> 9;
    int il = blockIdx.x & (NPTS - 1);
    int tid = threadIdx.x;
    {
        int base = (b * NPTS + tid) * 3;
        px[tid] = pos[base]; py[tid] = pos[base + 1]; pz[tid] = pos[base + 2];
    }
    __syncthreads();
    float xi = px[il], yi = py[il], zi = pz[il];
    {
        float dx = px[tid] - xi, dy = py[tid] - yi, dz = pz[tid] - zi;
        float d2 = dx * dx;
        d2 = d2 + dy * dy;
        d2 = d2 + dz * dz;
        keys[tid] = (((unsigned long long)__float_as_uint(d2)) << 32) | (unsigned)tid;
    }
    for (int k2 = 2; k2 <= NPTS; k2 <<= 1) {
        for (int j = k2 >> 1; j > 0; j >>= 1) {
            __syncthreads();
            int ixj = tid ^ j;
            if (ixj > tid) {
                unsigned long long a = keys[tid], c = keys[ixj];
                bool up = ((tid & k2) == 0);
                if ((a > c) == up) { keys[tid] = c; keys[ixj] = a; }
            }
        }
    }
    __syncthreads();
    if (tid < KNN) {
        int j = (int)(keys[tid] & 0xffffffffu);
        knn_out[(b * NPTS + il) * KNN + tid] = b * NPTS + j;
    }
}

// ---------------- GraphNorm fused: stats + apply (+optional relu) ----------------
__global__ __launch_bounds__(256) void gn_fused(const float* __restrict__ x, const float* __restrict__ ms,
                                                const float* __restrict__ w, const float* __restrict__ bn,
                                                int C, float* __restrict__ out, int relu) {
    __shared__ float r1[4][64], r2[4][64];
    __shared__ float As[64], Ss[64];
    int b = blockIdx.y;
    int cl = threadIdx.x & 63;
    int c = blockIdx.x * 64 + cl;
    int part = threadIdx.x >> 6;
    float s1 = 0.f, s2 = 0.f;
    if (c < C) {
        for (int n = part; n < NPTS; n += 4) {
            float v = x[(size_t)(b * NPTS + n) * C + c];
            s1 += v; s2 += v * v;
        }
    }
    r1[part][cl] = s1;
    r2[part][cl] = s2;
    __syncthreads();
    if (part == 0 && c < C) {
        s1 = r1[0][cl] + r1[1][cl] + r1[2][cl] + r1[3][cl];
        s2 = r2[0][cl] + r2[1][cl] + r2[2][cl] + r2[3][cl];
        float mean = s1 * (1.f / NPTS);
        float ex2 = s2 * (1.f / NPTS);
        float a = mean * ms[c];
        float var = ex2 - 2.f * a * mean + a * a;   // E[(x - mean*ms)^2]
        As[cl] = a;
        Ss[cl] = w[c] / sqrtf(var + EPSN);
    }
    __syncthreads();
    if (c < C) {
        float a = As[cl], sf = Ss[cl], bb = bn[c];
        for (int n = part; n < NPTS; n += 4) {
            size_t idx = (size_t)(b * NPTS + n) * C + c;
            float v = (x[idx] - a) * sf + bb;
            if (relu) v = fmaxf(v, 0.f);
            out[idx] = v;
        }
    }
}

// ---------------- Per-node MLP1 v2: each block computes 16 rows x ALL C cols ----------------
template<int CIN, int C>
__global__ __launch_bounds__(C) void node_kernel(const float* __restrict__ h, const float* __restrict__ pos,
                                                 const float* __restrict__ w1, const float* __restrict__ b1,
                                                 float* __restrict__ U, float* __restrict__ P) {
    constexpr int ROWS = 16;
    constexpr int KC = 64;
    constexpr int LDH = KC + 4;
    __shared__ float hs[ROWS][LDH];   // 4352 B
    const int c = threadIdx.x;
    const int n0 = blockIdx.x * ROWS;
    float acc[ROWS];
    #pragma unroll
    for (int r = 0; r < ROWS; ++r) acc[r] = 0.f;
    constexpr int NCHUNK = (CIN + KC - 1) / KC;
    #pragma unroll 1
    for (int s = 0; s < NCHUNK; ++s) {
        const int k0 = s * KC;
        const int kc = (CIN - k0 < KC) ? (CIN - k0) : KC;
        __syncthreads();
        for (int idx = c; idx < ROWS * kc; idx += C) {
            int r = idx / kc, k = idx - r * kc;
            hs[r][k] = h[(size_t)(n0 + r) * CIN + k0 + k];
        }
        __syncthreads();
        int k = 0;
        for (; k + 4 <= kc; k += 4) {
            float w0 = w1[(size_t)(k0 + k) * C + c];
            float w1v = w1[(size_t)(k0 + k + 1) * C + c];
            float w2v = w1[(size_t)(k0 + k + 2) * C + c];
            float w3v = w1[(size_t)(k0 + k + 3) * C + c];
            #pragma unroll
            for (int r = 0; r < ROWS; ++r) {
                f32x4 hv = *(const f32x4*)&hs[r][k];
                acc[r] = fmaf(hv[0], w0, acc[r]);
                acc[r] = fmaf(hv[1], w1v, acc[r]);
                acc[r] = fmaf(hv[2], w2v, acc[r]);
                acc[r] = fmaf(hv[3], w3v, acc[r]);
            }
        }
        for (; k < kc; ++k) {
            float wv = w1[(size_t)(k0 + k) * C + c];
            #pragma unroll
            for (int r = 0; r < ROWS; ++r)
                acc[r] = fmaf(hs[r][k], wv, acc[r]);
        }
    }
    float pacc[ROWS];
    #pragma unroll
    for (int r = 0; r < ROWS; ++r) pacc[r] = 0.f;
    #pragma unroll
    for (int e = 0; e < 3; ++e) {
        float wv = w1[(size_t)(CIN + e) * C + c];
        #pragma unroll
        for (int r = 0; r < ROWS; ++r)
            pacc[r] = fmaf(pos[(n0 + r) * 3 + e], wv, pacc[r]);
    }
    float bv = b1[c];
    #pragma unroll
    for (int r = 0; r < ROWS; ++r) {
        U[(size_t)(n0 + r) * C + c] = acc[r] + pacc[r] + bv;
        P[(size_t)(n0 + r) * C + c] = pacc[r];
    }
}

// ---------------- all 5 w2 -> blocked fp16 layouts, one launch ----------------
// dst[(ctg*(C/32)+s32)*512 + quad*128 + m*8 + j]  where n = ctg*16+m, k = s32*32+quad*8+j
__device__ __forceinline__ void w2cv(const float* __restrict__ src, unsigned short* __restrict__ dst,
                                     int off, int lg2c) {
    int C = 1 << lg2c;
    int k = off >> lg2c, n = off & (C - 1);
    int d = ((n >> 4) * (C / 32) + (k >> 5)) * 512 + ((k >> 3) & 3) * 128 + (n & 15) * 8 + (k & 7);
    dst[d] = f2h(src[off]);
}
__global__ __launch_bounds__(256) void w2tt_all(const float* __restrict__ wa, const float* __restrict__ wb,
                                                const float* __restrict__ wc, const float* __restrict__ wd,
                                                const float* __restrict__ we,
                                                unsigned short* __restrict__ oa, unsigned short* __restrict__ ob,
                                                unsigned short* __restrict__ oc, unsigned short* __restrict__ od,
                                                unsigned short* __restrict__ oe) {
    int idx = blockIdx.x * 256 + threadIdx.x;
    if (idx < 4096)                 w2cv(wa, oa, idx, 6);
    else if (idx < 20480)           w2cv(wb, ob, idx - 4096, 7);
    else if (idx < 86016)           w2cv(wc, oc, idx - 20480, 8);
    else if (idx < 348160)          w2cv(wd, od, idx - 86016, 9);
    else if (idx < 610304)          w2cv(we, oe, idx - 348160, 9);
}

// ---------------- Edge MLP2 + scatter-max ----------------
// One block per dst node (XCD-graph-swizzled). W waves; wave w owns cols [w*NCT*16,(w+1)*NCT*16).
// BK=32 per barrier iter; A-prefetch (U/P regs) + LDS dbuf. B loaded in MFMA phase.
template<int C, int W>
__global__ __launch_bounds__(W * 64, 4) void edge_kernel(const float* __restrict__ U, const float* __restrict__ P,
                                                         const int* __restrict__ knn, const unsigned short* __restrict__ w2t,
                                                         const float* __restrict__ b2, float* __restrict__ Y) {
    constexpr int NCT = C / (W * 16);    // col tiles per wave
    constexpr int EPT = 32 / W;          // staging cols per thread (8, 4, or 2)
    constexpr int S = C / 32;            // barrier iterations (one k32 each)
    constexpr int LD = 40;               // LDS row stride (halves)
    __shared__ unsigned short Tb[2][64 * LD];
    __shared__ int jn[64];
    const int bid = blockIdx.x;
    const int i = ((bid & 7) << 9) | (bid >> 3);   // XCD = bid%8 = graph(i): gather stays in one L2
    const int tid = threadIdx.x;
    const int wave = tid >> 6, lane = tid & 63, m = lane & 15, quad = lane >> 4;
    const int cw = wave * (NCT * 16);
    if (tid < 64) jn[tid] = knn[(size_t)i * KNN + tid];
    f32x4 acc[4][NCT];
    f32x4 zero = {0.f, 0.f, 0.f, 0.f};
    #pragma unroll
    for (int rt = 0; rt < 4; ++rt)
        #pragma unroll
        for (int ct = 0; ct < NCT; ++ct)
            acc[rt][ct] = zero;
    const int rr = tid / W;              // staging row 0..63
    const int c0 = (tid % W) * EPT;      // staging col base within k32 window
    __syncthreads();                     // jn visible
    const float* upr = U + (size_t)jn[rr] * C + c0;
    const float* ppr = P + (size_t)i * C + c0;
    float uf[EPT], pf[EPT];
    if constexpr (EPT == 8) {
        *(float4*)&uf[0] = *(const float4*)upr;       *(float4*)&uf[4] = *(const float4*)(upr + 4);
        *(float4*)&pf[0] = *(const float4*)ppr;       *(float4*)&pf[4] = *(const float4*)(ppr + 4);
    } else if constexpr (EPT == 4) {
        *(float4*)&uf[0] = *(const float4*)upr;       *(float4*)&pf[0] = *(const float4*)ppr;
    } else {
        *(float2*)&uf[0] = *(const float2*)upr;       *(float2*)&pf[0] = *(const float2*)ppr;
    }
    #pragma unroll 2
    for (int s = 0; s < S; ++s) {
        unsigned short* tb = Tb[s & 1];
        unsigned pks[EPT / 2];
        #pragma unroll
        for (int g = 0; g < EPT / 2; ++g)
            pks[g] = (unsigned)f2h(fmaxf(uf[2 * g] - pf[2 * g], 0.f)) |
                     ((unsigned)f2h(fmaxf(uf[2 * g + 1] - pf[2 * g + 1], 0.f)) << 16);
        if constexpr (EPT == 8)      *(uint4*)&tb[rr * LD + c0] = *(uint4*)pks;
        else if constexpr (EPT == 4) *(uint2*)&tb[rr * LD + c0] = *(uint2*)pks;
        else                         *(unsigned*)&tb[rr * LD + c0] = pks[0];
        if (s + 1 < S) {                 // A-prefetch next k32 window
            const float* un = upr + (s + 1) * 32;
            const float* pn = ppr + (s + 1) * 32;
            if constexpr (EPT == 8) {
                *(float4*)&uf[0] = *(const float4*)un;  *(float4*)&uf[4] = *(const float4*)(un + 4);
                *(float4*)&pf[0] = *(const float4*)pn;  *(float4*)&pf[4] = *(const float4*)(pn + 4);
            } else if constexpr (EPT == 4) {
                *(float4*)&uf[0] = *(const float4*)un;  *(float4*)&pf[0] = *(const float4*)pn;
            } else {
                *(float2*)&uf[0] = *(const float2*)un;  *(float2*)&pf[0] = *(const float2*)pn;
            }
        }
        __syncthreads();
        f16x8 a[4];
        #pragma unroll
        for (int rt = 0; rt < 4; ++rt)
            a[rt] = *(const f16x8*)&tb[(rt * 16 + m) * LD + quad * 8];
        #pragma unroll
        for (int ct = 0; ct < NCT; ++ct) {
            const f16x8 bb = *(const f16x8*)(w2t +
                (size_t)(((cw >> 4) + ct) * S + s) * 512 + quad * 128 + m * 8);
            #pragma unroll
            for (int rt = 0; rt < 4; ++rt)
                acc[rt][ct] = __builtin_amdgcn_mfma_f32_16x16x32_f16(a[rt], bb, acc[rt][ct], 0, 0, 0);
        }
    }
    #pragma unroll
    for (int ct = 0; ct < NCT; ++ct) {
        float vmax = -3.4e38f;
        #pragma unroll
        for (int rt = 0; rt < 4; ++rt) {
            vmax = fmaxf(vmax, acc[rt][ct][0]);
            vmax = fmaxf(vmax, acc[rt][ct][1]);
            vmax = fmaxf(vmax, acc[rt][ct][2]);
            vmax = fmaxf(vmax, acc[rt][ct][3]);
        }
        vmax = fmaxf(vmax, __shfl_xor(vmax, 16));
        vmax = fmaxf(vmax, __shfl_xor(vmax, 32));
        if (quad == 0) {
            int col = cw + ct * 16 + m;
            Y[(size_t)i * C + col] = vmax + b2[col];
        }
    }
}

// ---------------- Classifier: [N,512] @ [512,14] + b ----------------
__global__ __launch_bounds__(256) void cls_kernel(const float* __restrict__ h, const float* __restrict__ w,
                                                  const float* __restrict__ bias, float* __restrict__ out) {
    __shared__ float wl[512 * 14];
    int tid = threadIdx.x;
    for (int idx = tid; idx < 512 * 14; idx += 256) wl[idx] = w[idx];
    __syncthreads();
    if (tid < 224) {
        int nl = tid / 14, c = tid - nl * 14;
        int n = blockIdx.x * 16 + nl;
        float acc = bias[c];
        const float* hr = h + (size_t)n * 512;
        for (int k = 0; k < 512; ++k)
            acc += hr[k] * wl[k * 14 + c];
        out[(size_t)n * 14 + c] = acc;
    }
}

extern "C" void kernel_launch(void* const* d_in, const int* in_sizes, int n_in,
                              void* d_out, int out_size, void* d_ws, size_t ws_size,
                              hipStream_t stream) {
    const float* pos = (const float*)d_in[0];
    const float* gnw[6]; const float* gnb[6]; const float* gnms[6];
    for (int i = 0; i < 6; ++i) {
        gnw[i]  = (const float*)d_in[2 + 3 * i];
        gnb[i]  = (const float*)d_in[3 + 3 * i];
        gnms[i] = (const float*)d_in[4 + 3 * i];
    }
    const float* cw1[5]; const float* cb1[5]; const float* cw2[5]; const float* cb2[5];
    for (int i = 0; i < 5; ++i) {
        cw1[i] = (const float*)d_in[20 + 4 * i];
        cb1[i] = (const float*)d_in[21 + 4 * i];
        cw2[i] = (const float*)d_in[22 + 4 * i];
        cb2[i] = (const float*)d_in[23 + 4 * i];
    }
    const float* clsw = (const float*)d_in[40];
    const float* clsb = (const float*)d_in[41];
    float* out = (float*)d_out;

    char* ws = (char*)d_ws;
    int* knn             = (int*)(ws + 0);                 // 1 MB
    float* U             = (float*)(ws + 1048576);         // 8 MB
    float* P             = (float*)(ws + 9437184);         // 8 MB
    float* h             = (float*)(ws + 17825792);        // 8 MB
    float* y             = (float*)(ws + 26214400);        // 8 MB
    unsigned short* w2t0 = (unsigned short*)(ws + 34603008);  // 8 KB
    unsigned short* w2t1 = (unsigned short*)(ws + 34611200);  // 32 KB
    unsigned short* w2t2 = (unsigned short*)(ws + 34643968);  // 128 KB
    unsigned short* w2t3 = (unsigned short*)(ws + 34775040);  // 512 KB
    unsigned short* w2t4 = (unsigned short*)(ws + 35299328);  // 512 KB

    w2tt_all<<<(610304 + 255) / 256, 256, 0, stream>>>(cw2[0], cw2[1], cw2[2], cw2[3], cw2[4],
                                                       w2t0, w2t1, w2t2, w2t3, w2t4);
    knn_kernel<<<N_NODES, 512, 0, stream>>>(pos, knn);

    // gn1 on pos -> h [N,3] (no relu)
    gn_fused<<<dim3(1, NGRAPH), 256, 0, stream>>>(pos, gnms[0], gnw[0], gnb[0], 3, h, 0);

    // Layer 1: CIN=3, C=64
    node_kernel<3, 64><<<N_NODES / 16, 64, 0, stream>>>(h, pos, cw1[0], cb1[0], U, P);
    edge_kernel<64, 4><<<N_NODES, 256, 0, stream>>>(U, P, knn, w2t0, cb2[0], y);
    gn_fused<<<dim3(1, NGRAPH), 256, 0, stream>>>(y, gnms[1], gnw[1], gnb[1], 64, h, 1);

    // Layer 2: CIN=64, C=128
    node_kernel<64, 128><<<N_NODES / 16, 128, 0, stream>>>(h, pos, cw1[1], cb1[1], U, P);
    edge_kernel<128, 8><<<N_NODES, 512, 0, stream>>>(U, P, knn, w2t1, cb2[1], y);
    gn_fused<<<dim3(2, NGRAPH), 256, 0, stream>>>(y, gnms[2], gnw[2], gnb[2], 128, h, 1);

    // Layer 3: CIN=128, C=256
    node_kernel<128, 256><<<N_NODES / 16, 256, 0, stream>>>(h, pos, cw1[2], cb1[2], U, P);
    edge_kernel<256, 8><<<N_NODES, 512, 0, stream>>>(U, P, knn, w2t2, cb2[2], y);
    gn_fused<<<dim3(4, NGRAPH), 256, 0, stream>>>(y, gnms[3], gnw[3], gnb[3], 256, h, 1);

    // Layer 4: CIN=256, C=512
    node_kernel<256, 512><<<N_NODES / 16, 512, 0, stream>>>(h, pos, cw1[3], cb1[3], U, P);
    edge_kernel<512, 16><<<N_NODES, 1024, 0, stream>>>(U, P, knn, w2t3, cb2[3], y);
    gn_fused<<<dim3(8, NGRAPH), 256, 0, stream>>>(y, gnms[4], gnw[4], gnb[4], 512, h, 1);

    // Layer 5: CIN=512, C=512
    node_kernel<512, 512><<<N_NODES / 16, 512, 0, stream>>>(h, pos, cw1[4], cb1[4], U, P);
    edge_kernel<512, 16><<<N_NODES, 1024, 0, stream>>>(U, P, knn, w2t4, cb2[4], y);
    gn_fused<<<dim3(8, NGRAPH), 256, 0, stream>>>(y, gnms[5], gnw[5], gnb[5], 512, h, 1);

    cls_kernel<<<N_NODES / 16, 256, 0, stream>>>(h, clsw, clsb, out);
}

// Round 11
// 841.642 us; speedup vs baseline: 1.2522x; 1.2522x over previous
//
#include <hip/hip_runtime.h>
#include <stdint.h>

#define N_NODES 4096
#define NGRAPH 8
#define NPTS 512
#define KNN 64
#define EPSN 1e-5f

typedef _Float16 f16x8 __attribute__((ext_vector_type(8)));
typedef float f32x4 __attribute__((ext_vector_type(4)));

__device__ __forceinline__ unsigned short f2h(float f) {
    _Float16 h = (_Float16)f;   // RNE, v_cvt_f16_f32
    union { _Float16 h; unsigned short u; } cv; cv.h = h;
    return cv.u;
}

// ---------------- kNN: one block per dst point, bitonic sort of 512 (d2,idx) keys ----------------
__global__ __launch_bounds__(512) void knn_kernel(const float* __restrict__ pos, int* __restrict__ knn_out) {
#pragma clang fp contract(off)
    __shared__ float px[NPTS], py[NPTS], pz[NPTS];
    __shared__ unsigned long long keys[NPTS];
    int b = blockIdx.x >> 9;
    int il = blockIdx.x & (NPTS - 1);
    int tid = threadIdx.x;
    {
        int base = (b * NPTS + tid) * 3;
        px[tid] = pos[base]; py[tid] = pos[base + 1]; pz[tid] = pos[base + 2];
    }
    __syncthreads();
    float xi = px[il], yi = py[il], zi = pz[il];
    {
        float dx = px[tid] - xi, dy = py[tid] - yi, dz = pz[tid] - zi;
        float d2 = dx * dx;
        d2 = d2 + dy * dy;
        d2 = d2 + dz * dz;
        keys[tid] = (((unsigned long long)__float_as_uint(d2)) << 32) | (unsigned)tid;
    }
    for (int k2 = 2; k2 <= NPTS; k2 <<= 1) {
        for (int j = k2 >> 1; j > 0; j >>= 1) {
            __syncthreads();
            int ixj = tid ^ j;
            if (ixj > tid) {
                unsigned long long a = keys[tid], c = keys[ixj];
                bool up = ((tid & k2) == 0);
                if ((a > c) == up) { keys[tid] = c; keys[ixj] = a; }
            }
        }
    }
    __syncthreads();
    if (tid < KNN) {
        int j = (int)(keys[tid] & 0xffffffffu);
        knn_out[(b * NPTS + il) * KNN + tid] = b * NPTS + j;
    }
}

// ---------------- GraphNorm stats only: A = mean*ms, S = w/sqrt(var+eps) ----------------
__global__ __launch_bounds__(512) void gn_stats(const float* __restrict__ x, const float* __restrict__ ms,
                                                const float* __restrict__ w, int C,
                                                float* __restrict__ A, float* __restrict__ S) {
    __shared__ float r1[8][64], r2[8][64];
    int b = blockIdx.y;
    int cl = threadIdx.x & 63;
    int c = blockIdx.x * 64 + cl;
    int part = threadIdx.x >> 6;
    float s1 = 0.f, s2 = 0.f;
    if (c < C) {
        for (int n = part; n < NPTS; n += 8) {
            float v = x[(size_t)(b * NPTS + n) * C + c];
            s1 += v; s2 += v * v;
        }
    }
    r1[part][cl] = s1;
    r2[part][cl] = s2;
    __syncthreads();
    if (part == 0 && c < C) {
        s1 = 0.f; s2 = 0.f;
        #pragma unroll
        for (int p = 0; p < 8; ++p) { s1 += r1[p][cl]; s2 += r2[p][cl]; }
        float mean = s1 * (1.f / NPTS);
        float ex2 = s2 * (1.f / NPTS);
        float a = mean * ms[c];
        float var = ex2 - 2.f * a * mean + a * a;   // E[(x - mean*ms)^2]
        A[b * C + c] = a;
        S[b * C + c] = w[c] / sqrtf(var + EPSN);
    }
}

// ---------------- GraphNorm fused (stats+apply) — used for gn6 only ----------------
__global__ __launch_bounds__(256) void gn_fused(const float* __restrict__ x, const float* __restrict__ ms,
                                                const float* __restrict__ w, const float* __restrict__ bn,
                                                int C, float* __restrict__ out, int relu) {
    __shared__ float r1[4][64], r2[4][64];
    __shared__ float As[64], Ss[64];
    int b = blockIdx.y;
    int cl = threadIdx.x & 63;
    int c = blockIdx.x * 64 + cl;
    int part = threadIdx.x >> 6;
    float s1 = 0.f, s2 = 0.f;
    if (c < C) {
        for (int n = part; n < NPTS; n += 4) {
            float v = x[(size_t)(b * NPTS + n) * C + c];
            s1 += v; s2 += v * v;
        }
    }
    r1[part][cl] = s1;
    r2[part][cl] = s2;
    __syncthreads();
    if (part == 0 && c < C) {
        s1 = r1[0][cl] + r1[1][cl] + r1[2][cl] + r1[3][cl];
        s2 = r2[0][cl] + r2[1][cl] + r2[2][cl] + r2[3][cl];
        float mean = s1 * (1.f / NPTS);
        float ex2 = s2 * (1.f / NPTS);
        float a = mean * ms[c];
        float var = ex2 - 2.f * a * mean + a * a;
        As[cl] = a;
        Ss[cl] = w[c] / sqrtf(var + EPSN);
    }
    __syncthreads();
    if (c < C) {
        float a = As[cl], sf = Ss[cl], bb = bn[c];
        for (int n = part; n < NPTS; n += 4) {
            size_t idx = (size_t)(b * NPTS + n) * C + c;
            float v = (x[idx] - a) * sf + bb;
            if (relu) v = fmaxf(v, 0.f);
            out[idx] = v;
        }
    }
}

// ---------------- Per-node MLP1 with fused GraphNorm apply on input ----------------
// h_norm = (relu?)((y - A)*S + bn) applied on-the-fly while staging into LDS; h never materialized.
template<int CIN, int C, int RELU>
__global__ __launch_bounds__(C) void node_kernel(const float* __restrict__ y, const float* __restrict__ pos,
                                                 const float* __restrict__ A, const float* __restrict__ S,
                                                 const float* __restrict__ bnp,
                                                 const float* __restrict__ w1, const float* __restrict__ b1,
                                                 float* __restrict__ U, float* __restrict__ P) {
    constexpr int ROWS = 16;
    constexpr int KC = 64;
    constexpr int LDH = KC + 4;
    __shared__ float hs[ROWS][LDH];   // 4352 B
    const int c = threadIdx.x;
    const int n0 = blockIdx.x * ROWS;
    const int b = n0 >> 9;            // all 16 rows in one graph
    float acc[ROWS];
    #pragma unroll
    for (int r = 0; r < ROWS; ++r) acc[r] = 0.f;
    constexpr int NCHUNK = (CIN + KC - 1) / KC;
    #pragma unroll 1
    for (int s = 0; s < NCHUNK; ++s) {
        const int k0 = s * KC;
        const int kc = (CIN - k0 < KC) ? (CIN - k0) : KC;
        __syncthreads();
        for (int idx = c; idx < ROWS * kc; idx += C) {
            int r = idx / kc, k = idx - r * kc;
            int ch = k0 + k;
            float v = (y[(size_t)(n0 + r) * CIN + ch] - A[b * CIN + ch]) * S[b * CIN + ch] + bnp[ch];
            if (RELU) v = fmaxf(v, 0.f);
            hs[r][k] = v;
        }
        __syncthreads();
        int k = 0;
        for (; k + 4 <= kc; k += 4) {
            float w0 = w1[(size_t)(k0 + k) * C + c];
            float w1v = w1[(size_t)(k0 + k + 1) * C + c];
            float w2v = w1[(size_t)(k0 + k + 2) * C + c];
            float w3v = w1[(size_t)(k0 + k + 3) * C + c];
            #pragma unroll
            for (int r = 0; r < ROWS; ++r) {
                f32x4 hv = *(const f32x4*)&hs[r][k];
                acc[r] = fmaf(hv[0], w0, acc[r]);
                acc[r] = fmaf(hv[1], w1v, acc[r]);
                acc[r] = fmaf(hv[2], w2v, acc[r]);
                acc[r] = fmaf(hv[3], w3v, acc[r]);
            }
        }
        for (; k < kc; ++k) {
            float wv = w1[(size_t)(k0 + k) * C + c];
            #pragma unroll
            for (int r = 0; r < ROWS; ++r)
                acc[r] = fmaf(hs[r][k], wv, acc[r]);
        }
    }
    float pacc[ROWS];
    #pragma unroll
    for (int r = 0; r < ROWS; ++r) pacc[r] = 0.f;
    #pragma unroll
    for (int e = 0; e < 3; ++e) {
        float wv = w1[(size_t)(CIN + e) * C + c];
        #pragma unroll
        for (int r = 0; r < ROWS; ++r)
            pacc[r] = fmaf(pos[(n0 + r) * 3 + e], wv, pacc[r]);
    }
    float bv = b1[c];
    #pragma unroll
    for (int r = 0; r < ROWS; ++r) {
        U[(size_t)(n0 + r) * C + c] = acc[r] + pacc[r] + bv;
        P[(size_t)(n0 + r) * C + c] = pacc[r];
    }
}

// ---------------- all 5 w2 -> blocked fp16 layouts, one launch ----------------
__device__ __forceinline__ void w2cv(const float* __restrict__ src, unsigned short* __restrict__ dst,
                                     int off, int lg2c) {
    int C = 1 << lg2c;
    int k = off >> lg2c, n = off & (C - 1);
    int d = ((n >> 4) * (C / 32) + (k >> 5)) * 512 + ((k >> 3) & 3) * 128 + (n & 15) * 8 + (k & 7);
    dst[d] = f2h(src[off]);
}
__global__ __launch_bounds__(256) void w2tt_all(const float* __restrict__ wa, const float* __restrict__ wb,
                                                const float* __restrict__ wc, const float* __restrict__ wd,
                                                const float* __restrict__ we,
                                                unsigned short* __restrict__ oa, unsigned short* __restrict__ ob,
                                                unsigned short* __restrict__ oc, unsigned short* __restrict__ od,
                                                unsigned short* __restrict__ oe) {
    int idx = blockIdx.x * 256 + threadIdx.x;
    if (idx < 4096)                 w2cv(wa, oa, idx, 6);
    else if (idx < 20480)           w2cv(wb, ob, idx - 4096, 7);
    else if (idx < 86016)           w2cv(wc, oc, idx - 20480, 8);
    else if (idx < 348160)          w2cv(wd, od, idx - 86016, 9);
    else if (idx < 610304)          w2cv(we, oe, idx - 348160, 9);
}

// ---------------- Edge MLP2 + scatter-max (R9-proven shape) ----------------
template<int C, int W>
__global__ __launch_bounds__(W * 64, 4) void edge_kernel(const float* __restrict__ U, const float* __restrict__ P,
                                                         const int* __restrict__ knn, const unsigned short* __restrict__ w2t,
                                                         const float* __restrict__ b2, float* __restrict__ Y) {
    constexpr int NCT = C / (W * 16);    // col tiles per wave
    constexpr int EPT = 32 / W;          // staging cols per thread (8 or 4)
    constexpr int S = C / 32;            // barrier iterations (one k32 each)
    constexpr int LD = 40;               // LDS row stride (halves)
    __shared__ unsigned short Tb[2][64 * LD];
    __shared__ int jn[64];
    const int bid = blockIdx.x;
    const int i = ((bid & 7) << 9) | (bid >> 3);   // XCD = bid%8 = graph(i): gather stays in one L2
    const int tid = threadIdx.x;
    const int wave = tid >> 6, lane = tid & 63, m = lane & 15, quad = lane >> 4;
    const int cw = wave * (NCT * 16);
    if (tid < 64) jn[tid] = knn[(size_t)i * KNN + tid];
    f32x4 acc[4][NCT];
    f32x4 zero = {0.f, 0.f, 0.f, 0.f};
    #pragma unroll
    for (int rt = 0; rt < 4; ++rt)
        #pragma unroll
        for (int ct = 0; ct < NCT; ++ct)
            acc[rt][ct] = zero;
    const int rr = tid / W;              // staging row 0..63
    const int c0 = (tid % W) * EPT;      // staging col base within k32 window
    __syncthreads();                     // jn visible
    const float* upr = U + (size_t)jn[rr] * C + c0;
    const float* ppr = P + (size_t)i * C + c0;
    float4 uf[EPT / 4], pf[EPT / 4];
    #pragma unroll
    for (int g = 0; g < EPT / 4; ++g) {
        uf[g] = *(const float4*)(upr + g * 4);
        pf[g] = *(const float4*)(ppr + g * 4);
    }
    #pragma unroll 2
    for (int s = 0; s < S; ++s) {
        unsigned short* tb = Tb[s & 1];
        if constexpr (EPT == 8) {
            uint4 pk;
            pk.x = (unsigned)f2h(fmaxf(uf[0].x - pf[0].x, 0.f)) | ((unsigned)f2h(fmaxf(uf[0].y - pf[0].y, 0.f)) << 16);
            pk.y = (unsigned)f2h(fmaxf(uf[0].z - pf[0].z, 0.f)) | ((unsigned)f2h(fmaxf(uf[0].w - pf[0].w, 0.f)) << 16);
            pk.z = (unsigned)f2h(fmaxf(uf[1].x - pf[1].x, 0.f)) | ((unsigned)f2h(fmaxf(uf[1].y - pf[1].y, 0.f)) << 16);
            pk.w = (unsigned)f2h(fmaxf(uf[1].z - pf[1].z, 0.f)) | ((unsigned)f2h(fmaxf(uf[1].w - pf[1].w, 0.f)) << 16);
            *(uint4*)&tb[rr * LD + c0] = pk;
        } else {
            uint2 pk;
            pk.x = (unsigned)f2h(fmaxf(uf[0].x - pf[0].x, 0.f)) | ((unsigned)f2h(fmaxf(uf[0].y - pf[0].y, 0.f)) << 16);
            pk.y = (unsigned)f2h(fmaxf(uf[0].z - pf[0].z, 0.f)) | ((unsigned)f2h(fmaxf(uf[0].w - pf[0].w, 0.f)) << 16);
            *(uint2*)&tb[rr * LD + c0] = pk;
        }
        if (s + 1 < S) {                 // A-prefetch next k32 window
            #pragma unroll
            for (int g = 0; g < EPT / 4; ++g) {
                uf[g] = *(const float4*)(upr + (s + 1) * 32 + g * 4);
                pf[g] = *(const float4*)(ppr + (s + 1) * 32 + g * 4);
            }
        }
        __syncthreads();
        f16x8 a[4];
        #pragma unroll
        for (int rt = 0; rt < 4; ++rt)
            a[rt] = *(const f16x8*)&tb[(rt * 16 + m) * LD + quad * 8];
        #pragma unroll
        for (int ct = 0; ct < NCT; ++ct) {
            const f16x8 bb = *(const f16x8*)(w2t +
                (size_t)(((cw >> 4) + ct) * S + s) * 512 + quad * 128 + m * 8);
            #pragma unroll
            for (int rt = 0; rt < 4; ++rt)
                acc[rt][ct] = __builtin_amdgcn_mfma_f32_16x16x32_f16(a[rt], bb, acc[rt][ct], 0, 0, 0);
        }
    }
    #pragma unroll
    for (int ct = 0; ct < NCT; ++ct) {
        float vmax = -3.4e38f;
        #pragma unroll
        for (int rt = 0; rt < 4; ++rt) {
            vmax = fmaxf(vmax, acc[rt][ct][0]);
            vmax = fmaxf(vmax, acc[rt][ct][1]);
            vmax = fmaxf(vmax, acc[rt][ct][2]);
            vmax = fmaxf(vmax, acc[rt][ct][3]);
        }
        vmax = fmaxf(vmax, __shfl_xor(vmax, 16));
        vmax = fmaxf(vmax, __shfl_xor(vmax, 32));
        if (quad == 0) {
            int col = cw + ct * 16 + m;
            Y[(size_t)i * C + col] = vmax + b2[col];
        }
    }
}

// ---------------- Classifier: [N,512] @ [512,14] + b ----------------
__global__ __launch_bounds__(256) void cls_kernel(const float* __restrict__ h, const float* __restrict__ w,
                                                  const float* __restrict__ bias, float* __restrict__ out) {
    __shared__ float wl[512 * 14];
    int tid = threadIdx.x;
    for (int idx = tid; idx < 512 * 14; idx += 256) wl[idx] = w[idx];
    __syncthreads();
    if (tid < 224) {
        int nl = tid / 14, c = tid - nl * 14;
        int n = blockIdx.x * 16 + nl;
        float acc = bias[c];
        const float* hr = h + (size_t)n * 512;
        for (int k = 0; k < 512; ++k)
            acc += hr[k] * wl[k * 14 + c];
        out[(size_t)n * 14 + c] = acc;
    }
}

extern "C" void kernel_launch(void* const* d_in, const int* in_sizes, int n_in,
                              void* d_out, int out_size, void* d_ws, size_t ws_size,
                              hipStream_t stream) {
    const float* pos = (const float*)d_in[0];
    const float* gnw[6]; const float* gnb[6]; const float* gnms[6];
    for (int i = 0; i < 6; ++i) {
        gnw[i]  = (const float*)d_in[2 + 3 * i];
        gnb[i]  = (const float*)d_in[3 + 3 * i];
        gnms[i] = (const float*)d_in[4 + 3 * i];
    }
    const float* cw1[5]; const float* cb1[5]; const float* cw2[5]; const float* cb2[5];
    for (int i = 0; i < 5; ++i) {
        cw1[i] = (const float*)d_in[20 + 4 * i];
        cb1[i] = (const float*)d_in[21 + 4 * i];
        cw2[i] = (const float*)d_in[22 + 4 * i];
        cb2[i] = (const float*)d_in[23 + 4 * i];
    }
    const float* clsw = (const float*)d_in[40];
    const float* clsb = (const float*)d_in[41];
    float* out = (float*)d_out;

    char* ws = (char*)d_ws;
    int* knn             = (int*)(ws + 0);                 // 1 MB
    float* U             = (float*)(ws + 1048576);         // 8 MB
    float* P             = (float*)(ws + 9437184);         // 8 MB
    float* h             = (float*)(ws + 17825792);        // 8 MB
    float* y             = (float*)(ws + 26214400);        // 8 MB
    float* Aa            = (float*)(ws + 34603008);        // 16 KB
    float* Sa            = (float*)(ws + 34619392);        // 16 KB
    unsigned short* w2t0 = (unsigned short*)(ws + 34635776);  // 8 KB
    unsigned short* w2t1 = (unsigned short*)(ws + 34643968);  // 32 KB
    unsigned short* w2t2 = (unsigned short*)(ws + 34676736);  // 128 KB
    unsigned short* w2t3 = (unsigned short*)(ws + 34807808);  // 512 KB
    unsigned short* w2t4 = (unsigned short*)(ws + 35332096);  // 512 KB

    w2tt_all<<<(610304 + 255) / 256, 256, 0, stream>>>(cw2[0], cw2[1], cw2[2], cw2[3], cw2[4],
                                                       w2t0, w2t1, w2t2, w2t3, w2t4);
    knn_kernel<<<N_NODES, 512, 0, stream>>>(pos, knn);

    // Layer 1: gn1 stats on pos; apply fused into node1 (no relu)
    gn_stats<<<dim3(1, NGRAPH), 512, 0, stream>>>(pos, gnms[0], gnw[0], 3, Aa, Sa);
    node_kernel<3, 64, 0><<<N_NODES / 16, 64, 0, stream>>>(pos, pos, Aa, Sa, gnb[0], cw1[0], cb1[0], U, P);
    edge_kernel<64, 4><<<N_NODES, 256, 0, stream>>>(U, P, knn, w2t0, cb2[0], y);

    // Layer 2
    gn_stats<<<dim3(1, NGRAPH), 512, 0, stream>>>(y, gnms[1], gnw[1], 64, Aa, Sa);
    node_kernel<64, 128, 1><<<N_NODES / 16, 128, 0, stream>>>(y, pos, Aa, Sa, gnb[1], cw1[1], cb1[1], U, P);
    edge_kernel<128, 8><<<N_NODES, 512, 0, stream>>>(U, P, knn, w2t1, cb2[1], y);

    // Layer 3
    gn_stats<<<dim3(2, NGRAPH), 512, 0, stream>>>(y, gnms[2], gnw[2], 128, Aa, Sa);
    node_kernel<128, 256, 1><<<N_NODES / 16, 256, 0, stream>>>(y, pos, Aa, Sa, gnb[2], cw1[2], cb1[2], U, P);
    edge_kernel<256, 8><<<N_NODES, 512, 0, stream>>>(U, P, knn, w2t2, cb2[2], y);

    // Layer 4
    gn_stats<<<dim3(4, NGRAPH), 512, 0, stream>>>(y, gnms[3], gnw[3], 256, Aa, Sa);
    node_kernel<256, 512, 1><<<N_NODES / 16, 512, 0, stream>>>(y, pos, Aa, Sa, gnb[3], cw1[3], cb1[3], U, P);
    edge_kernel<512, 8><<<N_NODES, 512, 0, stream>>>(U, P, knn, w2t3, cb2[3], y);

    // Layer 5
    gn_stats<<<dim3(8, NGRAPH), 512, 0, stream>>>(y, gnms[4], gnw[4], 512, Aa, Sa);
    node_kernel<512, 512, 1><<<N_NODES / 16, 512, 0, stream>>>(y, pos, Aa, Sa, gnb[4], cw1[4], cb1[4], U, P);
    edge_kernel<512, 8><<<N_NODES, 512, 0, stream>>>(U, P, knn, w2t4, cb2[4], y);

    // gn6 (stats+apply, relu) -> h ; classifier
    gn_fused<<<dim3(8, NGRAPH), 256, 0, stream>>>(y, gnms[5], gnw[5], gnb[5], 512, h, 1);
    cls_kernel<<<N_NODES / 16, 256, 0, stream>>>(h, clsw, clsb, out);
}

// Round 12
// 828.920 us; speedup vs baseline: 1.2714x; 1.0153x over previous
//
#include <hip/hip_runtime.h>
#include <stdint.h>

#define N_NODES 4096
#define NGRAPH 8
#define NPTS 512
#define KNN 64
#define EPSN 1e-5f

typedef _Float16 f16x8 __attribute__((ext_vector_type(8)));
typedef float f32x4 __attribute__((ext_vector_type(4)));

__device__ __forceinline__ unsigned short f2h(float f) {
    _Float16 h = (_Float16)f;   // RNE, v_cvt_f16_f32
    union { _Float16 h; unsigned short u; } cv; cv.h = h;
    return cv.u;
}

// ---------------- kNN: ONE WAVE per dst point; barriers are single-wave (cheap) ----------------
__global__ __launch_bounds__(64) void knn_kernel(const float* __restrict__ pos, int* __restrict__ knn_out) {
#pragma clang fp contract(off)
    __shared__ float px[NPTS], py[NPTS], pz[NPTS];
    __shared__ unsigned long long keys[NPTS];
    int b = blockIdx.x >> 9;
    int il = blockIdx.x & (NPTS - 1);
    int tid = threadIdx.x;   // 0..63
    for (int n = tid; n < NPTS; n += 64) {
        int base = (b * NPTS + n) * 3;
        px[n] = pos[base]; py[n] = pos[base + 1]; pz[n] = pos[base + 2];
    }
    __syncthreads();
    float xi = px[il], yi = py[il], zi = pz[il];
    for (int n = tid; n < NPTS; n += 64) {
        float dx = px[n] - xi, dy = py[n] - yi, dz = pz[n] - zi;
        float d2 = dx * dx;
        d2 = d2 + dy * dy;
        d2 = d2 + dz * dz;
        keys[n] = (((unsigned long long)__float_as_uint(d2)) << 32) | (unsigned)n;
    }
    __syncthreads();
    for (int k2 = 2; k2 <= NPTS; k2 <<= 1) {
        for (int j = k2 >> 1; j > 0; j >>= 1) {
            #pragma unroll 4
            for (int p = 0; p < 4; ++p) {
                int pid = tid + p * 64;                         // 256 pairs
                int t = ((pid & ~(j - 1)) << 1) | (pid & (j - 1));  // bit j clear
                int ixj = t | j;
                unsigned long long a = keys[t], c = keys[ixj];
                bool up = ((t & k2) == 0);
                if ((a > c) == up) { keys[t] = c; keys[ixj] = a; }
            }
            __syncthreads();
        }
    }
    int j0 = (int)(keys[tid] & 0xffffffffu);
    knn_out[(b * NPTS + il) * KNN + tid] = b * NPTS + j0;
}

// ---------------- GraphNorm stats only: A = mean*ms, S = w/sqrt(var+eps) ----------------
__global__ __launch_bounds__(512) void gn_stats(const float* __restrict__ x, const float* __restrict__ ms,
                                                const float* __restrict__ w, int C,
                                                float* __restrict__ A, float* __restrict__ S) {
    __shared__ float r1[8][64], r2[8][64];
    int b = blockIdx.y;
    int cl = threadIdx.x & 63;
    int c = blockIdx.x * 64 + cl;
    int part = threadIdx.x >> 6;
    float s1 = 0.f, s2 = 0.f;
    if (c < C) {
        for (int n = part; n < NPTS; n += 8) {
            float v = x[(size_t)(b * NPTS + n) * C + c];
            s1 += v; s2 += v * v;
        }
    }
    r1[part][cl] = s1;
    r2[part][cl] = s2;
    __syncthreads();
    if (part == 0 && c < C) {
        s1 = 0.f; s2 = 0.f;
        #pragma unroll
        for (int p = 0; p < 8; ++p) { s1 += r1[p][cl]; s2 += r2[p][cl]; }
        float mean = s1 * (1.f / NPTS);
        float ex2 = s2 * (1.f / NPTS);
        float a = mean * ms[c];
        float var = ex2 - 2.f * a * mean + a * a;   // E[(x - mean*ms)^2]
        A[b * C + c] = a;
        S[b * C + c] = w[c] / sqrtf(var + EPSN);
    }
}

// ---------------- Per-node MLP1 with fused GraphNorm apply on input ----------------
template<int CIN, int C, int RELU>
__global__ __launch_bounds__(C) void node_kernel(const float* __restrict__ y, const float* __restrict__ pos,
                                                 const float* __restrict__ A, const float* __restrict__ S,
                                                 const float* __restrict__ bnp,
                                                 const float* __restrict__ w1, const float* __restrict__ b1,
                                                 float* __restrict__ U, float* __restrict__ P) {
    constexpr int ROWS = 16;
    constexpr int KC = 64;
    constexpr int LDH = KC + 4;
    __shared__ float hs[ROWS][LDH];   // 4352 B
    const int c = threadIdx.x;
    const int n0 = blockIdx.x * ROWS;
    const int b = n0 >> 9;            // all 16 rows in one graph
    float acc[ROWS];
    #pragma unroll
    for (int r = 0; r < ROWS; ++r) acc[r] = 0.f;
    constexpr int NCHUNK = (CIN + KC - 1) / KC;
    #pragma unroll 1
    for (int s = 0; s < NCHUNK; ++s) {
        const int k0 = s * KC;
        const int kc = (CIN - k0 < KC) ? (CIN - k0) : KC;
        __syncthreads();
        for (int idx = c; idx < ROWS * kc; idx += C) {
            int r = idx / kc, k = idx - r * kc;
            int ch = k0 + k;
            float v = (y[(size_t)(n0 + r) * CIN + ch] - A[b * CIN + ch]) * S[b * CIN + ch] + bnp[ch];
            if (RELU) v = fmaxf(v, 0.f);
            hs[r][k] = v;
        }
        __syncthreads();
        int k = 0;
        for (; k + 4 <= kc; k += 4) {
            float w0 = w1[(size_t)(k0 + k) * C + c];
            float w1v = w1[(size_t)(k0 + k + 1) * C + c];
            float w2v = w1[(size_t)(k0 + k + 2) * C + c];
            float w3v = w1[(size_t)(k0 + k + 3) * C + c];
            #pragma unroll
            for (int r = 0; r < ROWS; ++r) {
                f32x4 hv = *(const f32x4*)&hs[r][k];
                acc[r] = fmaf(hv[0], w0, acc[r]);
                acc[r] = fmaf(hv[1], w1v, acc[r]);
                acc[r] = fmaf(hv[2], w2v, acc[r]);
                acc[r] = fmaf(hv[3], w3v, acc[r]);
            }
        }
        for (; k < kc; ++k) {
            float wv = w1[(size_t)(k0 + k) * C + c];
            #pragma unroll
            for (int r = 0; r < ROWS; ++r)
                acc[r] = fmaf(hs[r][k], wv, acc[r]);
        }
    }
    float pacc[ROWS];
    #pragma unroll
    for (int r = 0; r < ROWS; ++r) pacc[r] = 0.f;
    #pragma unroll
    for (int e = 0; e < 3; ++e) {
        float wv = w1[(size_t)(CIN + e) * C + c];
        #pragma unroll
        for (int r = 0; r < ROWS; ++r)
            pacc[r] = fmaf(pos[(n0 + r) * 3 + e], wv, pacc[r]);
    }
    float bv = b1[c];
    #pragma unroll
    for (int r = 0; r < ROWS; ++r) {
        U[(size_t)(n0 + r) * C + c] = acc[r] + pacc[r] + bv;
        P[(size_t)(n0 + r) * C + c] = pacc[r];
    }
}

// ---------------- all 5 w2 -> blocked fp16 layouts, one launch ----------------
__device__ __forceinline__ void w2cv(const float* __restrict__ src, unsigned short* __restrict__ dst,
                                     int off, int lg2c) {
    int C = 1 << lg2c;
    int k = off >> lg2c, n = off & (C - 1);
    int d = ((n >> 4) * (C / 32) + (k >> 5)) * 512 + ((k >> 3) & 3) * 128 + (n & 15) * 8 + (k & 7);
    dst[d] = f2h(src[off]);
}
__global__ __launch_bounds__(256) void w2tt_all(const float* __restrict__ wa, const float* __restrict__ wb,
                                                const float* __restrict__ wc, const float* __restrict__ wd,
                                                const float* __restrict__ we,
                                                unsigned short* __restrict__ oa, unsigned short* __restrict__ ob,
                                                unsigned short* __restrict__ oc, unsigned short* __restrict__ od,
                                                unsigned short* __restrict__ oe) {
    int idx = blockIdx.x * 256 + threadIdx.x;
    if (idx < 4096)                 w2cv(wa, oa, idx, 6);
    else if (idx < 20480)           w2cv(wb, ob, idx - 4096, 7);
    else if (idx < 86016)           w2cv(wc, oc, idx - 20480, 8);
    else if (idx < 348160)          w2cv(wd, od, idx - 86016, 9);
    else if (idx < 610304)          w2cv(we, oe, idx - 348160, 9);
}

// ---------------- Edge MLP2 + scatter-max (R9 shape + bb0 cross-barrier prefetch) ----------------
template<int C, int W>
__global__ __launch_bounds__(W * 64, 4) void edge_kernel(const float* __restrict__ U, const float* __restrict__ P,
                                                         const int* __restrict__ knn, const unsigned short* __restrict__ w2t,
                                                         const float* __restrict__ b2, float* __restrict__ Y) {
    constexpr int NCT = C / (W * 16);    // col tiles per wave
    constexpr int EPT = 32 / W;          // staging cols per thread (8 or 4)
    constexpr int S = C / 32;            // barrier iterations (one k32 each)
    constexpr int LD = 40;               // LDS row stride (halves)
    __shared__ unsigned short Tb[2][64 * LD];
    __shared__ int jn[64];
    const int bid = blockIdx.x;
    const int i = ((bid & 7) << 9) | (bid >> 3);   // XCD = bid%8 = graph(i): gather stays in one L2
    const int tid = threadIdx.x;
    const int wave = tid >> 6, lane = tid & 63, m = lane & 15, quad = lane >> 4;
    const int cw = wave * (NCT * 16);
    if (tid < 64) jn[tid] = knn[(size_t)i * KNN + tid];
    f32x4 acc[4][NCT];
    f32x4 zero = {0.f, 0.f, 0.f, 0.f};
    #pragma unroll
    for (int rt = 0; rt < 4; ++rt)
        #pragma unroll
        for (int ct = 0; ct < NCT; ++ct)
            acc[rt][ct] = zero;
    const int rr = tid / W;              // staging row 0..63
    const int c0 = (tid % W) * EPT;      // staging col base within k32 window
    __syncthreads();                     // jn visible
    const float* upr = U + (size_t)jn[rr] * C + c0;
    const float* ppr = P + (size_t)i * C + c0;
    const unsigned short* wb0 = w2t + (size_t)((cw >> 4) * S) * 512 + quad * 128 + m * 8;  // ct=0 stream
    float4 uf[EPT / 4], pf[EPT / 4];
    #pragma unroll
    for (int g = 0; g < EPT / 4; ++g) {
        uf[g] = *(const float4*)(upr + g * 4);
        pf[g] = *(const float4*)(ppr + g * 4);
    }
    f16x8 b0 = *(const f16x8*)wb0;       // ct=0, s=0
    #pragma unroll 2
    for (int s = 0; s < S; ++s) {
        unsigned short* tb = Tb[s & 1];
        if constexpr (EPT == 8) {
            uint4 pk;
            pk.x = (unsigned)f2h(fmaxf(uf[0].x - pf[0].x, 0.f)) | ((unsigned)f2h(fmaxf(uf[0].y - pf[0].y, 0.f)) << 16);
            pk.y = (unsigned)f2h(fmaxf(uf[0].z - pf[0].z, 0.f)) | ((unsigned)f2h(fmaxf(uf[0].w - pf[0].w, 0.f)) << 16);
            pk.z = (unsigned)f2h(fmaxf(uf[1].x - pf[1].x, 0.f)) | ((unsigned)f2h(fmaxf(uf[1].y - pf[1].y, 0.f)) << 16);
            pk.w = (unsigned)f2h(fmaxf(uf[1].z - pf[1].z, 0.f)) | ((unsigned)f2h(fmaxf(uf[1].w - pf[1].w, 0.f)) << 16);
            *(uint4*)&tb[rr * LD + c0] = pk;
        } else {
            uint2 pk;
            pk.x = (unsigned)f2h(fmaxf(uf[0].x - pf[0].x, 0.f)) | ((unsigned)f2h(fmaxf(uf[0].y - pf[0].y, 0.f)) << 16);
            pk.y = (unsigned)f2h(fmaxf(uf[0].z - pf[0].z, 0.f)) | ((unsigned)f2h(fmaxf(uf[0].w - pf[0].w, 0.f)) << 16);
            *(uint2*)&tb[rr * LD + c0] = pk;
        }
        f16x8 b0n;
        if (s + 1 < S) {                 // A-prefetch + bb0-prefetch; drained at the barrier -> ready
            #pragma unroll
            for (int g = 0; g < EPT / 4; ++g) {
                uf[g] = *(const float4*)(upr + (s + 1) * 32 + g * 4);
                pf[g] = *(const float4*)(ppr + (s + 1) * 32 + g * 4);
            }
            b0n = *(const f16x8*)(wb0 + (size_t)(s + 1) * 512);
        }
        __syncthreads();
        f16x8 a[4];
        #pragma unroll
        for (int rt = 0; rt < 4; ++rt)
            a[rt] = *(const f16x8*)&tb[(rt * 16 + m) * LD + quad * 8];
        #pragma unroll
        for (int rt = 0; rt < 4; ++rt)
            acc[rt][0] = __builtin_amdgcn_mfma_f32_16x16x32_f16(a[rt], b0, acc[rt][0], 0, 0, 0);
        #pragma unroll
        for (int ct = 1; ct < NCT; ++ct) {
            const f16x8 bb = *(const f16x8*)(w2t +
                (size_t)(((cw >> 4) + ct) * S + s) * 512 + quad * 128 + m * 8);
            #pragma unroll
            for (int rt = 0; rt < 4; ++rt)
                acc[rt][ct] = __builtin_amdgcn_mfma_f32_16x16x32_f16(a[rt], bb, acc[rt][ct], 0, 0, 0);
        }
        b0 = b0n;
    }
    #pragma unroll
    for (int ct = 0; ct < NCT; ++ct) {
        float vmax = -3.4e38f;
        #pragma unroll
        for (int rt = 0; rt < 4; ++rt) {
            vmax = fmaxf(vmax, acc[rt][ct][0]);
            vmax = fmaxf(vmax, acc[rt][ct][1]);
            vmax = fmaxf(vmax, acc[rt][ct][2]);
            vmax = fmaxf(vmax, acc[rt][ct][3]);
        }
        vmax = fmaxf(vmax, __shfl_xor(vmax, 16));
        vmax = fmaxf(vmax, __shfl_xor(vmax, 32));
        if (quad == 0) {
            int col = cw + ct * 16 + m;
            Y[(size_t)i * C + col] = vmax + b2[col];
        }
    }
}

// ---------------- Classifier with fused gn6: out = relu(gn(y)) @ w + b ----------------
__global__ __launch_bounds__(256) void cls_kernel(const float* __restrict__ y, const float* __restrict__ A,
                                                  const float* __restrict__ S, const float* __restrict__ gnb,
                                                  const float* __restrict__ w, const float* __restrict__ bias,
                                                  float* __restrict__ out) {
    __shared__ float wl[512 * 14];    // 28 KB
    __shared__ float hn[16][512];     // 32 KB
    int tid = threadIdx.x;
    int n0 = blockIdx.x * 16;
    int b = n0 >> 9;
    for (int idx = tid; idx < 512 * 14; idx += 256) wl[idx] = w[idx];
    for (int idx = tid; idx < 16 * 512; idx += 256) {
        int r = idx >> 9, k = idx & 511;
        float v = (y[(size_t)(n0 + r) * 512 + k] - A[b * 512 + k]) * S[b * 512 + k] + gnb[k];
        hn[r][k] = fmaxf(v, 0.f);
    }
    __syncthreads();
    if (tid < 224) {
        int nl = tid / 14, c = tid - nl * 14;
        float acc = bias[c];
        for (int k = 0; k < 512; ++k)
            acc += hn[nl][k] * wl[k * 14 + c];
        out[(size_t)(n0 + nl) * 14 + c] = acc;
    }
}

extern "C" void kernel_launch(void* const* d_in, const int* in_sizes, int n_in,
                              void* d_out, int out_size, void* d_ws, size_t ws_size,
                              hipStream_t stream) {
    const float* pos = (const float*)d_in[0];
    const float* gnw[6]; const float* gnb[6]; const float* gnms[6];
    for (int i = 0; i < 6; ++i) {
        gnw[i]  = (const float*)d_in[2 + 3 * i];
        gnb[i]  = (const float*)d_in[3 + 3 * i];
        gnms[i] = (const float*)d_in[4 + 3 * i];
    }
    const float* cw1[5]; const float* cb1[5]; const float* cw2[5]; const float* cb2[5];
    for (int i = 0; i < 5; ++i) {
        cw1[i] = (const float*)d_in[20 + 4 * i];
        cb1[i] = (const float*)d_in[21 + 4 * i];
        cw2[i] = (const float*)d_in[22 + 4 * i];
        cb2[i] = (const float*)d_in[23 + 4 * i];
    }
    const float* clsw = (const float*)d_in[40];
    const float* clsb = (const float*)d_in[41];
    float* out = (float*)d_out;

    char* ws = (char*)d_ws;
    int* knn             = (int*)(ws + 0);                 // 1 MB
    float* U             = (float*)(ws + 1048576);         // 8 MB
    float* P             = (float*)(ws + 9437184);         // 8 MB
    float* y             = (float*)(ws + 26214400);        // 8 MB
    float* Aa            = (float*)(ws + 34603008);        // 16 KB
    float* Sa            = (float*)(ws + 34619392);        // 16 KB
    unsigned short* w2t0 = (unsigned short*)(ws + 34635776);  // 8 KB
    unsigned short* w2t1 = (unsigned short*)(ws + 34643968);  // 32 KB
    unsigned short* w2t2 = (unsigned short*)(ws + 34676736);  // 128 KB
    unsigned short* w2t3 = (unsigned short*)(ws + 34807808);  // 512 KB
    unsigned short* w2t4 = (unsigned short*)(ws + 35332096);  // 512 KB

    w2tt_all<<<(610304 + 255) / 256, 256, 0, stream>>>(cw2[0], cw2[1], cw2[2], cw2[3], cw2[4],
                                                       w2t0, w2t1, w2t2, w2t3, w2t4);
    knn_kernel<<<N_NODES, 64, 0, stream>>>(pos, knn);

    // Layer 1: gn1 stats on pos; apply fused into node1 (no relu)
    gn_stats<<<dim3(1, NGRAPH), 512, 0, stream>>>(pos, gnms[0], gnw[0], 3, Aa, Sa);
    node_kernel<3, 64, 0><<<N_NODES / 16, 64, 0, stream>>>(pos, pos, Aa, Sa, gnb[0], cw1[0], cb1[0], U, P);
    edge_kernel<64, 4><<<N_NODES, 256, 0, stream>>>(U, P, knn, w2t0, cb2[0], y);

    // Layer 2
    gn_stats<<<dim3(1, NGRAPH), 512, 0, stream>>>(y, gnms[1], gnw[1], 64, Aa, Sa);
    node_kernel<64, 128, 1><<<N_NODES / 16, 128, 0, stream>>>(y, pos, Aa, Sa, gnb[1], cw1[1], cb1[1], U, P);
    edge_kernel<128, 8><<<N_NODES, 512, 0, stream>>>(U, P, knn, w2t1, cb2[1], y);

    // Layer 3
    gn_stats<<<dim3(2, NGRAPH), 512, 0, stream>>>(y, gnms[2], gnw[2], 128, Aa, Sa);
    node_kernel<128, 256, 1><<<N_NODES / 16, 256, 0, stream>>>(y, pos, Aa, Sa, gnb[2], cw1[2], cb1[2], U, P);
    edge_kernel<256, 8><<<N_NODES, 512, 0, stream>>>(U, P, knn, w2t2, cb2[2], y);

    // Layer 4
    gn_stats<<<dim3(4, NGRAPH), 512, 0, stream>>>(y, gnms[3], gnw[3], 256, Aa, Sa);
    node_kernel<256, 512, 1><<<N_NODES / 16, 512, 0, stream>>>(y, pos, Aa, Sa, gnb[3], cw1[3], cb1[3], U, P);
    edge_kernel<512, 8><<<N_NODES, 512, 0, stream>>>(U, P, knn, w2t3, cb2[3], y);

    // Layer 5
    gn_stats<<<dim3(8, NGRAPH), 512, 0, stream>>>(y, gnms[4], gnw[4], 512, Aa, Sa);
    node_kernel<512, 512, 1><<<N_NODES / 16, 512, 0, stream>>>(y, pos, Aa, Sa, gnb[4], cw1[4], cb1[4], U, P);
    edge_kernel<512, 8><<<N_NODES, 512, 0, stream>>>(U, P, knn, w2t4, cb2[4], y);

    // gn6 stats + fused cls
    gn_stats<<<dim3(8, NGRAPH), 512, 0, stream>>>(y, gnms[5], gnw[5], 512, Aa, Sa);
    cls_kernel<<<N_NODES / 16, 256, 0, stream>>>(y, Aa, Sa, gnb[5], clsw, clsb, out);
}

// Round 13
// 775.980 us; speedup vs baseline: 1.3581x; 1.0682x over previous
//
#include <hip/hip_runtime.h>
#include <stdint.h>

#define N_NODES 4096
#define NGRAPH 8
#define NPTS 512
#define KNN 64
#define EPSN 1e-5f

typedef _Float16 f16x8 __attribute__((ext_vector_type(8)));
typedef float f32x4 __attribute__((ext_vector_type(4)));

__device__ __forceinline__ unsigned short f2h(float f) {
    _Float16 h = (_Float16)f;   // RNE, v_cvt_f16_f32
    union { _Float16 h; unsigned short u; } cv; cv.h = h;
    return cv.u;
}

// ---------------- kNN: ONE WAVE per dst point; barriers are single-wave (cheap) ----------------
__global__ __launch_bounds__(64) void knn_kernel(const float* __restrict__ pos, int* __restrict__ knn_out) {
#pragma clang fp contract(off)
    __shared__ float px[NPTS], py[NPTS], pz[NPTS];
    __shared__ unsigned long long keys[NPTS];
    int b = blockIdx.x >> 9;
    int il = blockIdx.x & (NPTS - 1);
    int tid = threadIdx.x;   // 0..63
    for (int n = tid; n < NPTS; n += 64) {
        int base = (b * NPTS + n) * 3;
        px[n] = pos[base]; py[n] = pos[base + 1]; pz[n] = pos[base + 2];
    }
    __syncthreads();
    float xi = px[il], yi = py[il], zi = pz[il];
    for (int n = tid; n < NPTS; n += 64) {
        float dx = px[n] - xi, dy = py[n] - yi, dz = pz[n] - zi;
        float d2 = dx * dx;
        d2 = d2 + dy * dy;
        d2 = d2 + dz * dz;
        keys[n] = (((unsigned long long)__float_as_uint(d2)) << 32) | (unsigned)n;
    }
    __syncthreads();
    for (int k2 = 2; k2 <= NPTS; k2 <<= 1) {
        for (int j = k2 >> 1; j > 0; j >>= 1) {
            #pragma unroll 4
            for (int p = 0; p < 4; ++p) {
                int pid = tid + p * 64;                         // 256 pairs
                int t = ((pid & ~(j - 1)) << 1) | (pid & (j - 1));  // bit j clear
                int ixj = t | j;
                unsigned long long a = keys[t], c = keys[ixj];
                bool up = ((t & k2) == 0);
                if ((a > c) == up) { keys[t] = c; keys[ixj] = a; }
            }
            __syncthreads();
        }
    }
    int j0 = (int)(keys[tid] & 0xffffffffu);
    knn_out[(b * NPTS + il) * KNN + tid] = b * NPTS + j0;
}

// ---------------- GraphNorm stats (used only for gn1 on pos) ----------------
__global__ __launch_bounds__(512) void gn_stats(const float* __restrict__ x, const float* __restrict__ ms,
                                                const float* __restrict__ w, int C,
                                                float* __restrict__ A, float* __restrict__ S) {
    __shared__ float r1[8][64], r2[8][64];
    int b = blockIdx.y;
    int cl = threadIdx.x & 63;
    int c = blockIdx.x * 64 + cl;
    int part = threadIdx.x >> 6;
    float s1 = 0.f, s2 = 0.f;
    if (c < C) {
        for (int n = part; n < NPTS; n += 8) {
            float v = x[(size_t)(b * NPTS + n) * C + c];
            s1 += v; s2 += v * v;
        }
    }
    r1[part][cl] = s1;
    r2[part][cl] = s2;
    __syncthreads();
    if (part == 0 && c < C) {
        s1 = 0.f; s2 = 0.f;
        #pragma unroll
        for (int p = 0; p < 8; ++p) { s1 += r1[p][cl]; s2 += r2[p][cl]; }
        float mean = s1 * (1.f / NPTS);
        float ex2 = s2 * (1.f / NPTS);
        float a = mean * ms[c];
        float var = ex2 - 2.f * a * mean + a * a;   // E[(x - mean*ms)^2]
        A[b * C + c] = a;
        S[b * C + c] = w[c] / sqrtf(var + EPSN);
    }
}

// ---------------- Per-node MLP1 with fused GraphNorm apply on input ----------------
// RAW=1: p1/p2 are per-graph atomic sums (Σy, Σy²); A,S derived in prologue.
// RAW=0: p1/p2 are precomputed A,S arrays.
template<int CIN, int C, int RELU, int RAW>
__global__ __launch_bounds__(C) void node_kernel(const float* __restrict__ y, const float* __restrict__ pos,
                                                 const float* __restrict__ p1, const float* __restrict__ p2,
                                                 const float* __restrict__ ms, const float* __restrict__ gw,
                                                 const float* __restrict__ bnp,
                                                 const float* __restrict__ w1, const float* __restrict__ b1,
                                                 float* __restrict__ U, float* __restrict__ P) {
    constexpr int ROWS = 16;
    constexpr int KC = 64;
    constexpr int LDH = KC + 4;
    __shared__ float hs[ROWS][LDH];   // 4352 B
    __shared__ float As_[CIN > 0 ? CIN : 1], Ss_[CIN > 0 ? CIN : 1];
    const int c = threadIdx.x;
    const int n0 = blockIdx.x * ROWS;
    const int b = n0 >> 9;            // all 16 rows in one graph
    if (RAW) {
        for (int ch = c; ch < CIN; ch += C) {
            float s1 = p1[b * CIN + ch], s2 = p2[b * CIN + ch];
            float mean = s1 * (1.f / NPTS);
            float a = mean * ms[ch];
            float var = s2 * (1.f / NPTS) - 2.f * a * mean + a * a;
            As_[ch] = a;
            Ss_[ch] = gw[ch] / sqrtf(var + EPSN);
        }
    }
    float acc[ROWS];
    #pragma unroll
    for (int r = 0; r < ROWS; ++r) acc[r] = 0.f;
    constexpr int NCHUNK = (CIN + KC - 1) / KC;
    #pragma unroll 1
    for (int s = 0; s < NCHUNK; ++s) {
        const int k0 = s * KC;
        const int kc = (CIN - k0 < KC) ? (CIN - k0) : KC;
        __syncthreads();
        for (int idx = c; idx < ROWS * kc; idx += C) {
            int r = idx / kc, k = idx - r * kc;
            int ch = k0 + k;
            float a = RAW ? As_[ch] : p1[b * CIN + ch];
            float sf = RAW ? Ss_[ch] : p2[b * CIN + ch];
            float v = (y[(size_t)(n0 + r) * CIN + ch] - a) * sf + bnp[ch];
            if (RELU) v = fmaxf(v, 0.f);
            hs[r][k] = v;
        }
        __syncthreads();
        int k = 0;
        for (; k + 4 <= kc; k += 4) {
            float w0 = w1[(size_t)(k0 + k) * C + c];
            float w1v = w1[(size_t)(k0 + k + 1) * C + c];
            float w2v = w1[(size_t)(k0 + k + 2) * C + c];
            float w3v = w1[(size_t)(k0 + k + 3) * C + c];
            #pragma unroll
            for (int r = 0; r < ROWS; ++r) {
                f32x4 hv = *(const f32x4*)&hs[r][k];
                acc[r] = fmaf(hv[0], w0, acc[r]);
                acc[r] = fmaf(hv[1], w1v, acc[r]);
                acc[r] = fmaf(hv[2], w2v, acc[r]);
                acc[r] = fmaf(hv[3], w3v, acc[r]);
            }
        }
        for (; k < kc; ++k) {
            float wv = w1[(size_t)(k0 + k) * C + c];
            #pragma unroll
            for (int r = 0; r < ROWS; ++r)
                acc[r] = fmaf(hs[r][k], wv, acc[r]);
        }
    }
    float pacc[ROWS];
    #pragma unroll
    for (int r = 0; r < ROWS; ++r) pacc[r] = 0.f;
    #pragma unroll
    for (int e = 0; e < 3; ++e) {
        float wv = w1[(size_t)(CIN + e) * C + c];
        #pragma unroll
        for (int r = 0; r < ROWS; ++r)
            pacc[r] = fmaf(pos[(n0 + r) * 3 + e], wv, pacc[r]);
    }
    float bv = b1[c];
    #pragma unroll
    for (int r = 0; r < ROWS; ++r) {
        U[(size_t)(n0 + r) * C + c] = acc[r] + pacc[r] + bv;
        P[(size_t)(n0 + r) * C + c] = pacc[r];
    }
}

// ---------------- all 5 w2 -> blocked fp16 layouts + zero the stat accumulators ----------------
__device__ __forceinline__ void w2cv(const float* __restrict__ src, unsigned short* __restrict__ dst,
                                     int off, int lg2c) {
    int C = 1 << lg2c;
    int k = off >> lg2c, n = off & (C - 1);
    int d = ((n >> 4) * (C / 32) + (k >> 5)) * 512 + ((k >> 3) & 3) * 128 + (n & 15) * 8 + (k & 7);
    dst[d] = f2h(src[off]);
}
__global__ __launch_bounds__(256) void w2tt_all(const float* __restrict__ wa, const float* __restrict__ wb,
                                                const float* __restrict__ wc, const float* __restrict__ wd,
                                                const float* __restrict__ we,
                                                unsigned short* __restrict__ oa, unsigned short* __restrict__ ob,
                                                unsigned short* __restrict__ oc, unsigned short* __restrict__ od,
                                                unsigned short* __restrict__ oe,
                                                float* __restrict__ accz) {
    int idx = blockIdx.x * 256 + threadIdx.x;
    if (idx < 40960) accz[idx] = 0.f;     // 5 layers x (sum1+sum2) x 4096
    if (idx < 4096)                 w2cv(wa, oa, idx, 6);
    else if (idx < 20480)           w2cv(wb, ob, idx - 4096, 7);
    else if (idx < 86016)           w2cv(wc, oc, idx - 20480, 8);
    else if (idx < 348160)          w2cv(wd, od, idx - 86016, 9);
    else if (idx < 610304)          w2cv(we, oe, idx - 348160, 9);
}

// ---------------- Edge MLP2 + scatter-max (R9 shape) + atomic GraphNorm stats ----------------
template<int C, int W>
__global__ __launch_bounds__(W * 64, 4) void edge_kernel(const float* __restrict__ U, const float* __restrict__ P,
                                                         const int* __restrict__ knn, const unsigned short* __restrict__ w2t,
                                                         const float* __restrict__ b2, float* __restrict__ Y,
                                                         float* __restrict__ sum1, float* __restrict__ sum2) {
    constexpr int NCT = C / (W * 16);    // col tiles per wave
    constexpr int EPT = 32 / W;          // staging cols per thread (8 or 4)
    constexpr int S = C / 32;            // barrier iterations (one k32 each)
    constexpr int LD = 40;               // LDS row stride (halves)
    __shared__ unsigned short Tb[2][64 * LD];
    __shared__ int jn[64];
    const int bid = blockIdx.x;
    const int i = ((bid & 7) << 9) | (bid >> 3);   // XCD = bid%8 = graph(i): gather stays in one L2
    const int tid = threadIdx.x;
    const int wave = tid >> 6, lane = tid & 63, m = lane & 15, quad = lane >> 4;
    const int cw = wave * (NCT * 16);
    if (tid < 64) jn[tid] = knn[(size_t)i * KNN + tid];
    f32x4 acc[4][NCT];
    f32x4 zero = {0.f, 0.f, 0.f, 0.f};
    #pragma unroll
    for (int rt = 0; rt < 4; ++rt)
        #pragma unroll
        for (int ct = 0; ct < NCT; ++ct)
            acc[rt][ct] = zero;
    const int rr = tid / W;              // staging row 0..63
    const int c0 = (tid % W) * EPT;      // staging col base within k32 window
    __syncthreads();                     // jn visible
    const float* upr = U + (size_t)jn[rr] * C + c0;
    const float* ppr = P + (size_t)i * C + c0;
    float4 uf[EPT / 4], pf[EPT / 4];
    #pragma unroll
    for (int g = 0; g < EPT / 4; ++g) {
        uf[g] = *(const float4*)(upr + g * 4);
        pf[g] = *(const float4*)(ppr + g * 4);
    }
    #pragma unroll 2
    for (int s = 0; s < S; ++s) {
        unsigned short* tb = Tb[s & 1];
        if constexpr (EPT == 8) {
            uint4 pk;
            pk.x = (unsigned)f2h(fmaxf(uf[0].x - pf[0].x, 0.f)) | ((unsigned)f2h(fmaxf(uf[0].y - pf[0].y, 0.f)) << 16);
            pk.y = (unsigned)f2h(fmaxf(uf[0].z - pf[0].z, 0.f)) | ((unsigned)f2h(fmaxf(uf[0].w - pf[0].w, 0.f)) << 16);
            pk.z = (unsigned)f2h(fmaxf(uf[1].x - pf[1].x, 0.f)) | ((unsigned)f2h(fmaxf(uf[1].y - pf[1].y, 0.f)) << 16);
            pk.w = (unsigned)f2h(fmaxf(uf[1].z - pf[1].z, 0.f)) | ((unsigned)f2h(fmaxf(uf[1].w - pf[1].w, 0.f)) << 16);
            *(uint4*)&tb[rr * LD + c0] = pk;
        } else {
            uint2 pk;
            pk.x = (unsigned)f2h(fmaxf(uf[0].x - pf[0].x, 0.f)) | ((unsigned)f2h(fmaxf(uf[0].y - pf[0].y, 0.f)) << 16);
            pk.y = (unsigned)f2h(fmaxf(uf[0].z - pf[0].z, 0.f)) | ((unsigned)f2h(fmaxf(uf[0].w - pf[0].w, 0.f)) << 16);
            *(uint2*)&tb[rr * LD + c0] = pk;
        }
        if (s + 1 < S) {                 // A-prefetch next k32 window
            #pragma unroll
            for (int g = 0; g < EPT / 4; ++g) {
                uf[g] = *(const float4*)(upr + (s + 1) * 32 + g * 4);
                pf[g] = *(const float4*)(ppr + (s + 1) * 32 + g * 4);
            }
        }
        __syncthreads();
        f16x8 a[4];
        #pragma unroll
        for (int rt = 0; rt < 4; ++rt)
            a[rt] = *(const f16x8*)&tb[(rt * 16 + m) * LD + quad * 8];
        #pragma unroll
        for (int ct = 0; ct < NCT; ++ct) {
            const f16x8 bb = *(const f16x8*)(w2t +
                (size_t)(((cw >> 4) + ct) * S + s) * 512 + quad * 128 + m * 8);
            #pragma unroll
            for (int rt = 0; rt < 4; ++rt)
                acc[rt][ct] = __builtin_amdgcn_mfma_f32_16x16x32_f16(a[rt], bb, acc[rt][ct], 0, 0, 0);
        }
    }
    const int gb = i >> 9;
    #pragma unroll
    for (int ct = 0; ct < NCT; ++ct) {
        float vmax = -3.4e38f;
        #pragma unroll
        for (int rt = 0; rt < 4; ++rt) {
            vmax = fmaxf(vmax, acc[rt][ct][0]);
            vmax = fmaxf(vmax, acc[rt][ct][1]);
            vmax = fmaxf(vmax, acc[rt][ct][2]);
            vmax = fmaxf(vmax, acc[rt][ct][3]);
        }
        vmax = fmaxf(vmax, __shfl_xor(vmax, 16));
        vmax = fmaxf(vmax, __shfl_xor(vmax, 32));
        if (quad == 0) {
            int col = cw + ct * 16 + m;
            float val = vmax + b2[col];
            Y[(size_t)i * C + col] = val;
            atomicAdd(&sum1[gb * C + col], val);
            atomicAdd(&sum2[gb * C + col], val * val);
        }
    }
}

// ---------------- Classifier with fused gn6 (stats from atomic sums) ----------------
__global__ __launch_bounds__(256) void cls_kernel(const float* __restrict__ y, const float* __restrict__ sum1,
                                                  const float* __restrict__ sum2, const float* __restrict__ ms,
                                                  const float* __restrict__ gw, const float* __restrict__ gnb,
                                                  const float* __restrict__ w, const float* __restrict__ bias,
                                                  float* __restrict__ out) {
    __shared__ float wl[512 * 14];      // 28672 B
    __shared__ _Float16 hn[16][520];    // 16640 B (pad 8 -> 2-way LDS aliasing only)
    __shared__ float As[512], Ss[512];  // 4096 B
    int tid = threadIdx.x;
    int n0 = blockIdx.x * 16;
    int b = n0 >> 9;
    for (int ch = tid; ch < 512; ch += 256) {
        float s1 = sum1[b * 512 + ch], s2 = sum2[b * 512 + ch];
        float mean = s1 * (1.f / NPTS);
        float a = mean * ms[ch];
        float var = s2 * (1.f / NPTS) - 2.f * a * mean + a * a;
        As[ch] = a;
        Ss[ch] = gw[ch] / sqrtf(var + EPSN);
    }
    for (int idx = tid; idx < 512 * 14; idx += 256) wl[idx] = w[idx];
    __syncthreads();
    for (int idx = tid; idx < 16 * 512; idx += 256) {
        int r = idx >> 9, k = idx & 511;
        float v = (y[(size_t)(n0 + r) * 512 + k] - As[k]) * Ss[k] + gnb[k];
        hn[r][k] = (_Float16)fmaxf(v, 0.f);
    }
    __syncthreads();
    if (tid < 224) {
        int nl = tid / 14, c = tid - nl * 14;
        float acc = bias[c];
        for (int k = 0; k < 512; ++k)
            acc += (float)hn[nl][k] * wl[k * 14 + c];
        out[(size_t)(n0 + nl) * 14 + c] = acc;
    }
}

extern "C" void kernel_launch(void* const* d_in, const int* in_sizes, int n_in,
                              void* d_out, int out_size, void* d_ws, size_t ws_size,
                              hipStream_t stream) {
    const float* pos = (const float*)d_in[0];
    const float* gnw[6]; const float* gnb[6]; const float* gnms[6];
    for (int i = 0; i < 6; ++i) {
        gnw[i]  = (const float*)d_in[2 + 3 * i];
        gnb[i]  = (const float*)d_in[3 + 3 * i];
        gnms[i] = (const float*)d_in[4 + 3 * i];
    }
    const float* cw1[5]; const float* cb1[5]; const float* cw2[5]; const float* cb2[5];
    for (int i = 0; i < 5; ++i) {
        cw1[i] = (const float*)d_in[20 + 4 * i];
        cb1[i] = (const float*)d_in[21 + 4 * i];
        cw2[i] = (const float*)d_in[22 + 4 * i];
        cb2[i] = (const float*)d_in[23 + 4 * i];
    }
    const float* clsw = (const float*)d_in[40];
    const float* clsb = (const float*)d_in[41];
    float* out = (float*)d_out;

    char* ws = (char*)d_ws;
    int* knn             = (int*)(ws + 0);                 // 1 MB
    float* U             = (float*)(ws + 1048576);         // 8 MB
    float* P             = (float*)(ws + 9437184);         // 8 MB
    float* y             = (float*)(ws + 26214400);        // 8 MB
    float* Aa            = (float*)(ws + 34603008);        // 16 KB
    float* Sa            = (float*)(ws + 34619392);        // 16 KB
    unsigned short* w2t0 = (unsigned short*)(ws + 34635776);  // 8 KB
    unsigned short* w2t1 = (unsigned short*)(ws + 34643968);  // 32 KB
    unsigned short* w2t2 = (unsigned short*)(ws + 34676736);  // 128 KB
    unsigned short* w2t3 = (unsigned short*)(ws + 34807808);  // 512 KB
    unsigned short* w2t4 = (unsigned short*)(ws + 35332096);  // 512 KB
    float* acc           = (float*)(ws + 35856384);           // 160 KB: 5 x (4096+4096) floats
    float* s1l[5]; float* s2l[5];
    for (int l = 0; l < 5; ++l) { s1l[l] = acc + l * 8192; s2l[l] = s1l[l] + 4096; }

    w2tt_all<<<(610304 + 255) / 256, 256, 0, stream>>>(cw2[0], cw2[1], cw2[2], cw2[3], cw2[4],
                                                       w2t0, w2t1, w2t2, w2t3, w2t4, acc);
    knn_kernel<<<N_NODES, 64, 0, stream>>>(pos, knn);

    // Layer 1: gn1 stats on pos; apply fused into node1 (no relu)
    gn_stats<<<dim3(1, NGRAPH), 512, 0, stream>>>(pos, gnms[0], gnw[0], 3, Aa, Sa);
    node_kernel<3, 64, 0, 0><<<N_NODES / 16, 64, 0, stream>>>(pos, pos, Aa, Sa, gnms[0], gnw[0], gnb[0], cw1[0], cb1[0], U, P);
    edge_kernel<64, 4><<<N_NODES, 256, 0, stream>>>(U, P, knn, w2t0, cb2[0], y, s1l[0], s2l[0]);

    // Layer 2 (stats from L1 edge atomics)
    node_kernel<64, 128, 1, 1><<<N_NODES / 16, 128, 0, stream>>>(y, pos, s1l[0], s2l[0], gnms[1], gnw[1], gnb[1], cw1[1], cb1[1], U, P);
    edge_kernel<128, 8><<<N_NODES, 512, 0, stream>>>(U, P, knn, w2t1, cb2[1], y, s1l[1], s2l[1]);

    // Layer 3
    node_kernel<128, 256, 1, 1><<<N_NODES / 16, 256, 0, stream>>>(y, pos, s1l[1], s2l[1], gnms[2], gnw[2], gnb[2], cw1[2], cb1[2], U, P);
    edge_kernel<256, 8><<<N_NODES, 512, 0, stream>>>(U, P, knn, w2t2, cb2[2], y, s1l[2], s2l[2]);

    // Layer 4
    node_kernel<256, 512, 1, 1><<<N_NODES / 16, 512, 0, stream>>>(y, pos, s1l[2], s2l[2], gnms[3], gnw[3], gnb[3], cw1[3], cb1[3], U, P);
    edge_kernel<512, 8><<<N_NODES, 512, 0, stream>>>(U, P, knn, w2t3, cb2[3], y, s1l[3], s2l[3]);

    // Layer 5
    node_kernel<512, 512, 1, 1><<<N_NODES / 16, 512, 0, stream>>>(y, pos, s1l[3], s2l[3], gnms[4], gnw[4], gnb[4], cw1[4], cb1[4], U, P);
    edge_kernel<512, 8><<<N_NODES, 512, 0, stream>>>(U, P, knn, w2t4, cb2[4], y, s1l[4], s2l[4]);

    // gn6 (stats from L5 edge atomics) fused into classifier
    cls_kernel<<<N_NODES / 16, 256, 0, stream>>>(y, s1l[4], s2l[4], gnms[5], gnw[5], gnb[5], clsw, clsb, out);
}